// Round 6
// baseline (161.689 us; speedup 1.0000x reference)
//
#include <hip/hip_runtime.h>

typedef unsigned char u8;
typedef float f32x4 __attribute__((ext_vector_type(4)));
typedef float f32x16 __attribute__((ext_vector_type(16)));

#define LL 4096
#define PSTR 72               // P row stride (bytes), 32x64 P tile + pad
#define SCALE 16.0f           // x pre-scale before fp8
#define GSCALE (1.0f/256.0f)  // undo SCALE^2 on the gram
#define FREQC (-0.03597789207803197f)   // -ln(10000)/256

__device__ __forceinline__ long LCAST(uint2 v) { return __builtin_bit_cast(long, v); }

typedef __attribute__((address_space(3))) u8 lds_u8;
typedef __attribute__((address_space(1))) u8 glb_u8;
__device__ __forceinline__ void dma16(const u8* g, u8* l) {
  __builtin_amdgcn_global_load_lds((const glb_u8*)g, (lds_u8*)l, 16, 0, 0);
}

// ---------------- prep1 (verbatim R5 — validated): fp8 convert, swizzled layouts ----------------
// xbf: row r (256 B): 8-B chunk c stored at ((c ^ (r&31))*8).
// xT : d-row (4096 B) split into 32 j-segments of 128 B; chunk c in segment at ((c ^ (d&15))*8).
__global__ __launch_bounds__(256) void prep1(const float* __restrict__ x, u8* __restrict__ xbf,
                                             u8* __restrict__ xT, float* __restrict__ sq) {
  __shared__ u8 T[16 * 264];
  const int blk = blockIdx.x;
  const int b = blk >> 8, r0 = (blk & 255) << 4;
  const int tid = threadIdx.x;
  const long rowbase = (long)(b << 12) + r0;
  const float4* x4 = (const float4*)x + rowbase * 64;
  unsigned* xb4 = (unsigned*)xbf + rowbase * 64;
  #pragma unroll
  for (int i = 0; i < 4; ++i) {
    int idx = i * 256 + tid;
    float4 v = x4[idx];
    float s = v.x * v.x + v.y * v.y + v.z * v.z + v.w * v.w;
    #pragma unroll
    for (int o = 32; o; o >>= 1) s += __shfl_xor(s, o);
    int row = idx >> 6, dw = idx & 63;
    if ((tid & 63) == 0) sq[rowbase + row] = s;
    int pk = __builtin_amdgcn_cvt_pk_fp8_f32(v.x * SCALE, v.y * SCALE, 0, false);
    pk = __builtin_amdgcn_cvt_pk_fp8_f32(v.z * SCALE, v.w * SCALE, pk, true);
    int sdw = (((dw >> 1) ^ ((r0 + row) & 31)) << 1) | (dw & 1);
    xb4[row * 64 + sdw] = (unsigned)pk;
    *(unsigned*)(T + row * 264 + dw * 4) = (unsigned)pk;
  }
  __syncthreads();
  unsigned ob[4];
  #pragma unroll
  for (int jj = 0; jj < 4; ++jj) {
    unsigned b0 = T[(4 * jj + 0) * 264 + tid];
    unsigned b1 = T[(4 * jj + 1) * 264 + tid];
    unsigned b2 = T[(4 * jj + 2) * 264 + tid];
    unsigned b3 = T[(4 * jj + 3) * 264 + tid];
    ob[jj] = b0 | (b1 << 8) | (b2 << 16) | (b3 << 24);
  }
  u8* drow = xT + ((((long)(b << 8) + tid) << 12)) + ((r0 >> 7) << 7);
  const int cb = (r0 & 127) >> 3, key = tid & 15;
  *(uint2*)(drow + ((cb ^ key) << 3)) = *(uint2*)(ob);
  *(uint2*)(drow + (((cb + 1) ^ key) << 3)) = *(uint2*)(ob + 2);
}

// ---------------- main fused kernel ----------------
// 512 blocks x 512 thr, 2 blocks/CU (4 waves/SIMD) -> cross-block phase overlap.
// Block = (batch, 32 Q rows). K-tile 64, 64 iters, dbuf LDS K/V via global_load_lds.
// mm1 (16x16x32 fp8, S^T): wave w -> j-strip 16*(w&3), i-strip 16*(w>>2).
// mm2 (32x32x16 fp8): wave w -> O[32][32w..32w+31]; A = P (LDS), B = V tile (LDS).
__global__ __launch_bounds__(512, 4) void tpe_main(
    const u8* __restrict__ xbf, const u8* __restrict__ xT,
    const float* __restrict__ sqv,
    const float* __restrict__ x, float* __restrict__ out) {
  __shared__ u8 Kt[2][16384];    // K tile 64 rows x 256 B (row-swizzled, as in xbf)
  __shared__ u8 Vt[2][16384];    // V tile 256 d-rows x 64 B (chunk-swizzled, key d&7)
  __shared__ u8 Ps[32 * PSTR];
  __shared__ float lred[8][32];
  __shared__ float linv[32];

  const int tid = threadIdx.x;
  const int w = tid >> 6;
  const int lane = tid & 63;
  const int l15 = lane & 15, l31 = lane & 31;
  const int q4 = lane >> 4;   // 0..3
  const int q2 = lane >> 5;   // 0..1
  const int wj = w & 3;       // j-strip
  const int wi = w >> 2;      // i-strip

  // XCD pinning: batch -> XCD pair (2 MB fp8 set stays L2-hot)
  const int blk = blockIdx.x;
  const int b = (blk & 7) >> 1;
  const int qt = ((blk >> 3) << 1) | (blk & 1);   // 0..127
  const int q0 = qt << 5;
  const long bL = (long)b * LL;

  // Q fragments: each wave needs only its 16-row i-strip (16 VGPRs)
  uint2 qf[8];
  {
    const int row = q0 + 16 * wi + l15;
    const u8* qrow = xbf + ((bL + row) << 8);
    const int key = row & 31;
    #pragma unroll
    for (int s = 0; s < 8; ++s)
      qf[s] = *(const uint2*)(qrow + (((q4 + 4 * s) ^ key) << 3));
  }
  const float qa = -0.5f * sqv[bL + q0 + 16 * wi + l15];

  f32x16 oacc;
  #pragma unroll
  for (int k = 0; k < 16; ++k) oacc[k] = 0.f;
  float rsacc = 0.f;

  const u8* kbat = xbf + (bL << 8);
  const long vbat = ((long)(b << 8)) << 12;

  // prologue DMA: tile 0 -> buffer 0
  #pragma unroll
  for (int c = 0; c < 2; ++c) {
    int idx = c * 512 + tid;
    dma16(kbat + idx * 16, &Kt[0][idx * 16]);
  }
  #pragma unroll
  for (int c = 0; c < 2; ++c) {
    int idx = c * 512 + tid;
    int d = idx >> 2, c16 = idx & 3;
    dma16(xT + vbat + ((long)d << 12) + (((d >> 3) & 1) << 6) + c16 * 16, &Vt[0][idx * 16]);
  }
  __syncthreads();

  for (int it = 0; it < 64; ++it) {
    const int cur = it & 1;
    const int j0 = it << 6;
    // async DMA next tile into the other buffer
    if (it < 63) {
      const int g = it + 1;
      const int jn = g << 6;
      #pragma unroll
      for (int c = 0; c < 2; ++c) {
        int idx = c * 512 + tid;
        dma16(kbat + ((long)g << 14) + idx * 16, &Kt[cur ^ 1][idx * 16]);
      }
      const int sg = jn >> 7, h = (jn >> 6) & 1;
      #pragma unroll
      for (int c = 0; c < 2; ++c) {
        int idx = c * 512 + tid;
        int d = idx >> 2, c16 = idx & 3;
        dma16(xT + vbat + ((long)d << 12) + sg * 128 + (((h ^ (d >> 3)) & 1) << 6) + c16 * 16,
              &Vt[cur ^ 1][idx * 16]);
      }
    }
    float4 skv4 = *(const float4*)(sqv + bL + j0 + 16 * wj + 4 * q4);
    // ---- mm1: S^T = K.Q^T from LDS K-tile ----
    const u8* kt = Kt[cur];
    const int krow = 16 * wj + l15;
    const int kkey = krow & 31;
    f32x4 sacc;
    sacc[0] = 0.f; sacc[1] = 0.f; sacc[2] = 0.f; sacc[3] = 0.f;
    #pragma unroll
    for (int s = 0; s < 8; ++s) {
      uint2 kf = *(const uint2*)(kt + krow * 256 + (((q4 + 4 * s) ^ kkey) << 3));
      sacc = __builtin_amdgcn_mfma_f32_16x16x32_fp8_fp8(LCAST(kf), LCAST(qf[s]), sacc, 0, 0, 0);
    }
    // ---- P = exp(min(0, g - 0.5||q||^2 - 0.5||k||^2)) -> LDS ----
    {   // lane: P[i = 16wi + l15][j = 16wj + 4q4 + 0..3]
      float p0 = __expf(fminf(fmaf(sacc[0], GSCALE, qa + skv4.x), 0.f));
      float p1 = __expf(fminf(fmaf(sacc[1], GSCALE, qa + skv4.y), 0.f));
      float p2 = __expf(fminf(fmaf(sacc[2], GSCALE, qa + skv4.z), 0.f));
      float p3 = __expf(fminf(fmaf(sacc[3], GSCALE, qa + skv4.w), 0.f));
      rsacc += (p0 + p1) + (p2 + p3);
      int pk = __builtin_amdgcn_cvt_pk_fp8_f32(p0, p1, 0, false);
      pk = __builtin_amdgcn_cvt_pk_fp8_f32(p2, p3, pk, true);
      *(int*)(Ps + (16 * wi + l15) * PSTR + 16 * wj + 4 * q4) = pk;
    }
    __syncthreads();   // B1: P ready (also drains this iter's DMA)
    // ---- mm2: O += P V from LDS ----
    const u8* vt = Vt[cur];
    const int d = 32 * w + l31;                 // this wave's O columns
    const u8* vrow = vt + ((32 * w + l31) << 6);
    const int vkey = l31 & 7;
    #pragma unroll
    for (int s = 0; s < 4; ++s) {
      uint2 bv = *(const uint2*)(vrow + (((2 * s + q2) ^ vkey) << 3));
      long a = *(const long*)(Ps + l31 * PSTR + 16 * s + 8 * q2);
      oacc = __builtin_amdgcn_mfma_f32_32x32x16_fp8_fp8(a, LCAST(bv), oacc, 0, 0, 0);
    }
    __syncthreads();   // B2: tile + P consumed before overwrite
  }

  // ---- epilogue: rowsum reduce; out = O/(16*l) + x + pe(inline) ----
  {
    float r = rsacc;
    r += __shfl_xor(r, 16);
    r += __shfl_xor(r, 32);
    if (lane < 16) lred[w][16 * wi + l15] = r;
  }
  __syncthreads();
  if (tid < 32) {
    const int wb = (tid >> 4) << 2;
    float s = lred[wb][tid] + lred[wb + 1][tid] + lred[wb + 2][tid] + lred[wb + 3][tid];
    linv[tid] = 0.0625f / s;   // 1/16 undoes V pre-scale
  }
  __syncthreads();
  const int col = 32 * w + l31;
  const float freq = __expf((float)(col & ~1) * FREQC);
  #pragma unroll
  for (int reg = 0; reg < 16; ++reg) {
    int row = 4 * q2 + (reg & 3) + 8 * (reg >> 2);
    int l = q0 + row;
    float ang = (float)l * freq;
    float pv = (col & 1) ? __cosf(ang) : __sinf(ang);
    long off = ((bL + l) << 8) + col;
    out[off] = oacc[reg] * linv[row] + x[off] + pv;
  }
}

extern "C" void kernel_launch(void* const* d_in, const int* in_sizes, int n_in,
                              void* d_out, int out_size, void* d_ws, size_t ws_size,
                              hipStream_t stream) {
  const float* x = (const float*)d_in[0];
  float* out = (float*)d_out;
  char* ws = (char*)d_ws;
  u8* xbf = (u8*)ws;                       // 4,194,304 B  (fp8 x, swizzled rows)
  u8* xT = (u8*)(ws + 4194304);            // 4,194,304 B  (fp8 x^T, swizzled segments)
  float* sq = (float*)(ws + 8388608);      //    65,536 B
  prep1<<<1024, 256, 0, stream>>>(x, xbf, xT, sq);
  tpe_main<<<512, 512, 0, stream>>>(xbf, xT, sq, x, out);
}